// Round 7
// baseline (289.242 us; speedup 1.0000x reference)
//
#include <hip/hip_runtime.h>
#include <hip/hip_bf16.h>
#include <math.h>

#define N_NODES 100000
#define N_EDGES 400000
#define N_PAIRS 100000
#define NBINS   200000   // (rel, dst) bins

typedef short short8_t __attribute__((ext_vector_type(8)));
typedef float f32x4    __attribute__((ext_vector_type(4)));

__device__ __forceinline__ ushort f2bf(float f) {
    uint u = __float_as_uint(f);
    u += 0x7fffu + ((u >> 16) & 1u);          // RNE
    return (ushort)(u >> 16);
}
__device__ __forceinline__ float bf2f(ushort b) {
    return __uint_as_float(((uint)b) << 16);
}
__device__ __forceinline__ uint packbf(float a, float b) {
    return (uint)f2bf(a) | ((uint)f2bf(b) << 16);
}

#define GLDS16(gp, lp) \
    __builtin_amdgcn_global_load_lds((const __attribute__((address_space(1))) uint*)(gp), \
                                     (__attribute__((address_space(3))) uint*)(lp), 16, 0, 0)

template<int N> __device__ __forceinline__ void waitvm() {
    if constexpr (N == 0)      asm volatile("s_waitcnt vmcnt(0)" ::: "memory");
    else if constexpr (N == 2) asm volatile("s_waitcnt vmcnt(2)" ::: "memory");
    else if constexpr (N == 3) asm volatile("s_waitcnt vmcnt(3)" ::: "memory");
    else if constexpr (N == 4) asm volatile("s_waitcnt vmcnt(4)" ::: "memory");
    else if constexpr (N == 6) asm volatile("s_waitcnt vmcnt(6)" ::: "memory");
    else if constexpr (N == 8) asm volatile("s_waitcnt vmcnt(8)" ::: "memory");
}

// ---------------------------------------------------------------------------
// fp32 -> bf16 cast (vectorized, grid-stride)
// ---------------------------------------------------------------------------
__global__ void cast_kernel(const float* __restrict__ in, ushort* __restrict__ outp, int n4) {
    int i = blockIdx.x * 256 + threadIdx.x;
    int stride = gridDim.x * 256;
    for (; i < n4; i += stride) {
        float4 v = ((const float4*)in)[i];
        ushort4 o;
        o.x = f2bf(v.x); o.y = f2bf(v.y); o.z = f2bf(v.z); o.w = f2bf(v.w);
        ((ushort4*)outp)[i] = o;
    }
}

// ---------------------------------------------------------------------------
// Weight repacks (bf16, K-major rows Wt[n][k])
// ---------------------------------------------------------------------------
__global__ void wlin_kernel(const float* __restrict__ w, ushort* __restrict__ wt, int K) {
    int i = blockIdx.x * 256 + threadIdx.x;    // 128*K
    if (i >= 128 * K) return;
    int n = i / K, k = i - n * K;
    wt[i] = f2bf(w[(size_t)k * 128 + n]);
}
__global__ void wc1_kernel(const float* __restrict__ root, const float* __restrict__ w,
                           ushort* __restrict__ wt) {
    int i = blockIdx.x * 256 + threadIdx.x;    // 256*384
    if (i >= 256 * 384) return;
    int n = i / 384, k = i % 384;
    float v;
    if (k < 128) v = root[(size_t)k * 256 + n];
    else         v = w[(size_t)(k - 128) * 256 + n];   // [2,128,256] contiguous
    wt[(size_t)n * 384 + k] = f2bf(v);
}
__global__ void wc2_kernel(const float* __restrict__ root, const float* __restrict__ w,
                           ushort* __restrict__ wt) {
    int i = blockIdx.x * 256 + threadIdx.x;    // 384*256
    if (i >= 384 * 256) return;
    int n = i / 256, k = i % 256;
    float v;
    if (n < 128) v = root[(size_t)k * 128 + n];
    else         v = w[((size_t)((n >> 7) - 1) * 256 + k) * 128 + (n & 127)];
    wt[(size_t)n * 256 + k] = f2bf(v);
}

// ---------------------------------------------------------------------------
// CSR build: histogram -> exclusive scan (3 kernels) -> fill
// ---------------------------------------------------------------------------
__global__ void hist_kernel(const int* __restrict__ dst, const int* __restrict__ et,
                            int* __restrict__ cnt) {
    int e = blockIdx.x * 256 + threadIdx.x;
    if (e < N_EDGES) atomicAdd(&cnt[et[e] * N_NODES + dst[e]], 1);
}

__global__ __launch_bounds__(1024) void scan1_kernel(const int* __restrict__ cnt,
                                                     int* __restrict__ ptr,
                                                     int* __restrict__ aux) {
    __shared__ int s[1024];
    int i = blockIdx.x * 1024 + threadIdx.x;
    int v = (i < NBINS) ? cnt[i] : 0;
    s[threadIdx.x] = v;
    __syncthreads();
    for (int off = 1; off < 1024; off <<= 1) {
        int t = (threadIdx.x >= off) ? s[threadIdx.x - off] : 0;
        __syncthreads();
        s[threadIdx.x] += t;
        __syncthreads();
    }
    if (i < NBINS) ptr[i] = s[threadIdx.x] - v;          // block-exclusive
    if (threadIdx.x == 1023) aux[blockIdx.x] = s[1023];  // block total
}

__global__ void scan2_kernel(int* __restrict__ aux, int nblk) {
    __shared__ int s[256];
    int v = (threadIdx.x < nblk) ? aux[threadIdx.x] : 0;
    s[threadIdx.x] = v;
    __syncthreads();
    for (int off = 1; off < 256; off <<= 1) {
        int t = (threadIdx.x >= off) ? s[threadIdx.x - off] : 0;
        __syncthreads();
        s[threadIdx.x] += t;
        __syncthreads();
    }
    if (threadIdx.x < nblk) aux[threadIdx.x] = s[threadIdx.x] - v;  // exclusive
}

__global__ void scan3_kernel(const int* __restrict__ aux, int* __restrict__ ptr,
                             int* __restrict__ cursor) {
    int i = blockIdx.x * 256 + threadIdx.x;
    if (i < NBINS) {
        int val = ptr[i] + aux[i >> 10];
        ptr[i] = val;
        cursor[i] = val;
    }
    if (i == 0) ptr[NBINS] = N_EDGES;
}

__global__ void fill_kernel(const int* __restrict__ src, const int* __restrict__ dst,
                            const int* __restrict__ et, int* __restrict__ cursor,
                            int* __restrict__ esorted) {
    int e = blockIdx.x * 256 + threadIdx.x;
    if (e < N_EDGES) {
        int b = et[e] * N_NODES + dst[e];
        int pos = atomicAdd(&cursor[b], 1);
        esorted[pos] = src[e];
    }
}

// ---------------------------------------------------------------------------
// Layer-1 gather-mean: one wave per dst node, both relations, unroll-2.
// ---------------------------------------------------------------------------
__global__ void gather1_kernel(const int* __restrict__ ptr, const int* __restrict__ es,
                               ushort* __restrict__ A1) {
    int d = blockIdx.x * 4 + (threadIdx.x >> 6);
    if (d >= N_NODES) return;
    int lane = threadIdx.x & 63;
    int p0 = ptr[d],           p1 = ptr[d + 1];
    int q0 = ptr[N_NODES + d], q1 = ptr[N_NODES + d + 1];
    int n0 = p1 - p0, n1 = q1 - q0;
    int n  = n0 > n1 ? n0 : n1;
    float a0 = 0, a1 = 0, b0 = 0, b1 = 0;
    for (int k = 0; k < n; k += 2) {
        uint v00 = 0, v01 = 0, v10 = 0, v11 = 0;
        if (k < n0)     v00 = *(const uint*)(A1 + (size_t)es[p0 + k] * 384 + lane * 2);
        if (k + 1 < n0) v01 = *(const uint*)(A1 + (size_t)es[p0 + k + 1] * 384 + lane * 2);
        if (k < n1)     v10 = *(const uint*)(A1 + (size_t)es[q0 + k] * 384 + lane * 2);
        if (k + 1 < n1) v11 = *(const uint*)(A1 + (size_t)es[q0 + k + 1] * 384 + lane * 2);
        a0 += bf2f((ushort)(v00 & 0xffffu)) + bf2f((ushort)(v01 & 0xffffu));
        a1 += bf2f((ushort)(v00 >> 16))     + bf2f((ushort)(v01 >> 16));
        b0 += bf2f((ushort)(v10 & 0xffffu)) + bf2f((ushort)(v11 & 0xffffu));
        b1 += bf2f((ushort)(v10 >> 16))     + bf2f((ushort)(v11 >> 16));
    }
    float i0 = n0 ? 1.0f / (float)n0 : 0.0f;
    float i1 = n1 ? 1.0f / (float)n1 : 0.0f;
    uint* row = (uint*)(A1 + (size_t)d * 384);
    row[64  + lane] = packbf(a0 * i0, a1 * i0);
    row[128 + lane] = packbf(b0 * i1, b1 * i1);
}

// ---------------------------------------------------------------------------
// Layer-2 combine: z[d] = H[d][0:128] + mean_r0 H[s][128:256] + mean_r1 H[s][256:384]
// One wave per dst node, unroll-2. z output bf16.
// ---------------------------------------------------------------------------
__global__ void combine2_kernel(const int* __restrict__ ptr, const int* __restrict__ es,
                                const ushort* __restrict__ H, ushort* __restrict__ zb) {
    int d = blockIdx.x * 4 + (threadIdx.x >> 6);
    if (d >= N_NODES) return;
    int lane = threadIdx.x & 63;
    int p0 = ptr[d],           p1 = ptr[d + 1];
    int q0 = ptr[N_NODES + d], q1 = ptr[N_NODES + d + 1];
    int n0 = p1 - p0, n1 = q1 - q0;
    int n  = n0 > n1 ? n0 : n1;
    uint rv = *(const uint*)(H + (size_t)d * 384 + lane * 2);
    float r0 = bf2f((ushort)(rv & 0xffffu)), r1 = bf2f((ushort)(rv >> 16));
    float a0 = 0, a1 = 0, b0 = 0, b1 = 0;
    for (int k = 0; k < n; k += 2) {
        uint v00 = 0, v01 = 0, v10 = 0, v11 = 0;
        if (k < n0)     v00 = *(const uint*)(H + (size_t)es[p0 + k] * 384 + 128 + lane * 2);
        if (k + 1 < n0) v01 = *(const uint*)(H + (size_t)es[p0 + k + 1] * 384 + 128 + lane * 2);
        if (k < n1)     v10 = *(const uint*)(H + (size_t)es[q0 + k] * 384 + 256 + lane * 2);
        if (k + 1 < n1) v11 = *(const uint*)(H + (size_t)es[q0 + k + 1] * 384 + 256 + lane * 2);
        a0 += bf2f((ushort)(v00 & 0xffffu)) + bf2f((ushort)(v01 & 0xffffu));
        a1 += bf2f((ushort)(v00 >> 16))     + bf2f((ushort)(v01 >> 16));
        b0 += bf2f((ushort)(v10 & 0xffffu)) + bf2f((ushort)(v11 & 0xffffu));
        b1 += bf2f((ushort)(v10 >> 16))     + bf2f((ushort)(v11 >> 16));
    }
    float i0 = n0 ? 1.0f / (float)n0 : 0.0f;
    float i1 = n1 ? 1.0f / (float)n1 : 0.0f;
    uint* orow = (uint*)(zb + (size_t)d * 128);
    orow[lane] = packbf(r0 + a0 * i0 + b0 * i1, r1 + a1 * i0 + b1 * i1);
}

// ---------------------------------------------------------------------------
// Full-N MFMA GEMM: out[row][col] = A[row][:]@Wt[col][:] + bias(col<BIASN).
// Tile 128 x BN (BN = full output width), 8 waves (2x4), wave tile 64 x BN/4.
// 2-slot double-buffered LDS (keeps >=2 blocks/CU resident for cross-block
// latency hiding), global_load_lds width-16, counted vmcnt (never 0 mid-loop),
// XOR-swizzled LDS (pre-swizzled global source + swizzled read).
// ---------------------------------------------------------------------------
template<int KTOT, int BN, int OST, int BIASN, bool RELU>
__global__ __launch_bounds__(512)
void mfma_gemm_kernel(const ushort* __restrict__ A, const ushort* __restrict__ Wt,
                      const float* __restrict__ bias, ushort* __restrict__ outp,
                      int nrows) {
    constexpr int FC = BN / 64;           // frag-cols per wave
    constexpr int LB = BN / 128;          // B loads per thread per K-step
    constexpr int L  = 1 + LB;            // total loads per thread per K-step
    __shared__ short As[2][128 * 32];
    __shared__ short Bs[2][BN * 32];
    const int t  = threadIdx.x;
    const int m0 = blockIdx.x * 128;
    const int lane = t & 63, w = t >> 6;
    const int wr = w >> 2, wcl = w & 3;   // 2 x 4 wave grid
    const int l15 = lane & 15, l4 = lane >> 4;

    // staging: thread t owns A chunk t (row=t>>2, stored chunk t&3) and B
    // chunks t+i*512. Source chunk pre-swizzled: c_log = c_st ^ ((row>>1)&3).
    const int arow = t >> 2;
    const int sw_a = (((t & 3) ^ ((arow >> 1) & 3))) * 8;
    int rg = m0 + arow; if (rg >= nrows) rg = nrows - 1;
    const ushort* ap = A + (size_t)rg * KTOT + sw_a;
    const ushort* bp[LB];
#pragma unroll
    for (int i = 0; i < LB; i++) {
        int ch = t + i * 512;
        int brow = ch >> 2;
        bp[i] = Wt + (size_t)brow * KTOT + (((ch & 3) ^ ((brow >> 1) & 3))) * 8;
    }

#define STAGE(slot, kg) do { \
        GLDS16(ap + (kg), &As[slot][t * 8]); \
        _Pragma("unroll") \
        for (int i_ = 0; i_ < LB; i_++) \
            GLDS16(bp[i_] + (kg), &Bs[slot][(t + i_ * 512) * 8]); \
    } while (0)

    f32x4 acc[4][FC];
#pragma unroll
    for (int j = 0; j < FC; j++) {
        int col = wcl * (FC * 16) + j * 16 + l15;
        float bv = (col < BIASN) ? bias[col] : 0.0f;
        f32x4 tmp = {bv, bv, bv, bv};
#pragma unroll
        for (int i = 0; i < 4; i++) acc[i][j] = tmp;
    }

    // read-side swizzle: logical chunk l4 lives at stored chunk l4^((row>>1)&3),
    // and (row>>1)&3 == (l15>>1)&3 for every fragment row (bases are mult. of 8).
    const int xr = (l4 ^ ((l15 >> 1) & 3)) * 8;

    STAGE(0, 0);
    constexpr int NSTEP = KTOT / 32;
    for (int ks = 0; ks < NSTEP; ks++) {
        const int b = ks & 1;
        if (ks + 1 < NSTEP) {
            STAGE(b ^ 1, (ks + 1) * 32);
            waitvm<L>();                           // slot b done; next slot in flight
        } else {
            waitvm<0>();
        }
        asm volatile("s_barrier" ::: "memory");    // slot b staged for all waves
        short8_t af[4], bfr[FC];
#pragma unroll
        for (int i = 0; i < 4; i++)
            af[i] = *(short8_t*)&As[b][(wr * 64 + i * 16 + l15) * 32 + xr];
#pragma unroll
        for (int j = 0; j < FC; j++)
            bfr[j] = *(short8_t*)&Bs[b][(wcl * (FC * 16) + j * 16 + l15) * 32 + xr];
#pragma unroll
        for (int i = 0; i < 4; i++)
#pragma unroll
            for (int j = 0; j < FC; j++)
                acc[i][j] = __builtin_amdgcn_mfma_f32_16x16x32_bf16(af[i], bfr[j], acc[i][j], 0, 0, 0);
        asm volatile("s_barrier" ::: "memory");    // reads done before slot b re-stage
    }
#undef STAGE

#pragma unroll
    for (int i = 0; i < 4; i++) {
#pragma unroll
        for (int r = 0; r < 4; r++) {
            int row = m0 + wr * 64 + i * 16 + l4 * 4 + r;
            if (row < nrows) {
#pragma unroll
                for (int j = 0; j < FC; j++) {
                    int col = wcl * (FC * 16) + j * 16 + l15;
                    float v = acc[i][j][r];
                    if (RELU) v = fmaxf(v, 0.0f);
                    outp[(size_t)row * OST + col] = f2bf(v);
                }
            }
        }
    }
}

// ---------------------------------------------------------------------------
// Decode: out[p] = sigmoid( z[s]·fcw[0:128] + z[d]·fcw[128:256] + fcb ), z bf16
// ---------------------------------------------------------------------------
__global__ void decode_kernel(const ushort* __restrict__ zb, const int* __restrict__ dec,
                              const float* __restrict__ fcw, const float* __restrict__ fcb,
                              float* __restrict__ out) {
    int wid  = blockIdx.x * 4 + (threadIdx.x >> 6);
    int lane = threadIdx.x & 63;
    if (wid >= N_PAIRS) return;
    int s = dec[wid];
    int d = dec[N_PAIRS + wid];
    uint vs = ((const uint*)(zb + (size_t)s * 128))[lane];
    uint vd = ((const uint*)(zb + (size_t)d * 128))[lane];
    float v = bf2f((ushort)(vs & 0xffffu)) * fcw[2 * lane]
            + bf2f((ushort)(vs >> 16))     * fcw[2 * lane + 1]
            + bf2f((ushort)(vd & 0xffffu)) * fcw[128 + 2 * lane]
            + bf2f((ushort)(vd >> 16))     * fcw[128 + 2 * lane + 1];
#pragma unroll
    for (int off = 32; off > 0; off >>= 1) v += __shfl_down(v, off);
    if (lane == 0) out[wid] = 1.0f / (1.0f + expf(-(v + fcb[0])));
}

// ---------------------------------------------------------------------------
extern "C" void kernel_launch(void* const* d_in, const int* in_sizes, int n_in,
                              void* d_out, int out_size, void* d_ws, size_t ws_size,
                              hipStream_t stream) {
    const float* x0        = (const float*)d_in[0];
    const float* x1        = (const float*)d_in[1];
    const int*   edge_idx  = (const int*)  d_in[2];
    const int*   edge_type = (const int*)  d_in[3];
    const int*   dec_index = (const int*)  d_in[4];
    const float* lin0_w    = (const float*)d_in[5];
    const float* lin0_b    = (const float*)d_in[6];
    const float* lin1_w    = (const float*)d_in[7];
    const float* lin1_b    = (const float*)d_in[8];
    const float* conv1_w   = (const float*)d_in[9];
    const float* conv1_root= (const float*)d_in[10];
    const float* conv1_b   = (const float*)d_in[11];
    const float* conv2_w   = (const float*)d_in[12];
    const float* conv2_root= (const float*)d_in[13];
    const float* conv2_b   = (const float*)d_in[14];
    const float* fc_w      = (const float*)d_in[15];
    const float* fc_b      = (const float*)d_in[16];
    float* out = (float*)d_out;

    // ---- workspace layout (bytes), ~151.6 MB; H aliases A1, zb aliases y1 ----
    char* W = (char*)d_ws;
    ushort* A1    = (ushort*)(W + 0);            // 76,800,000 B [100k][384] = [x|agg0|agg1]
    ushort* H     = (ushort*)(W + 0);            // alias (A1 dead after gemm1)
    ushort* y1    = (ushort*)(W + 76800000);     // 51,200,000 B [100k][256]
    ushort* zb    = (ushort*)(W + 76800000);     // alias: [100k][128] bf16 (y1 dead after gemm2)
    int*    cnt   = (int*)   (W + 128000000);
    int*    ptrb  = (int*)   (W + 128800000);
    int*    cursor= (int*)   (W + 129600016);
    int*    aux   = (int*)   (W + 130400016);
    int*    esort = (int*)   (W + 130404112);
    ushort* wc1   = (ushort*)(W + 132004112);    // [256][384] bf16
    ushort* wc2   = (ushort*)(W + 132200720);    // [384][256] bf16
    ushort* wl0   = (ushort*)(W + 132397328);    // [128][128] bf16
    ushort* wl1   = (ushort*)(W + 132430096);    // [128][64]  bf16
    ushort* x0bf  = (ushort*)(W + 132446480);    // [50000][128] bf16
    ushort* x1bf  = (ushort*)(W + 145246480);    // [50000][64]  bf16

    const int* esrc = edge_idx;
    const int* edst = edge_idx + N_EDGES;

    // 0) zero histogram
    hipMemsetAsync(cnt, 0, (size_t)NBINS * sizeof(int), stream);

    // 1) casts + weight repacks
    cast_kernel<<<2048, 256, 0, stream>>>(x0, x0bf, 50000 * 128 / 4);
    cast_kernel<<<2048, 256, 0, stream>>>(x1, x1bf, 50000 * 64 / 4);
    wlin_kernel<<<64, 256, 0, stream>>>(lin0_w, wl0, 128);
    wlin_kernel<<<32, 256, 0, stream>>>(lin1_w, wl1, 64);
    wc1_kernel<<<(256 * 384 + 255) / 256, 256, 0, stream>>>(conv1_root, conv1_w, wc1);
    wc2_kernel<<<(384 * 256 + 255) / 256, 256, 0, stream>>>(conv2_root, conv2_w, wc2);

    // 2) CSR build over (rel,dst)
    hist_kernel<<<(N_EDGES + 255) / 256, 256, 0, stream>>>(edst, edge_type, cnt);
    scan1_kernel<<<(NBINS + 1023) / 1024, 1024, 0, stream>>>(cnt, ptrb, aux);
    scan2_kernel<<<1, 256, 0, stream>>>(aux, (NBINS + 1023) / 1024);
    scan3_kernel<<<(NBINS + 255) / 256, 256, 0, stream>>>(aux, ptrb, cursor);
    fill_kernel<<<(N_EDGES + 255) / 256, 256, 0, stream>>>(esrc, edst, edge_type,
                                                           cursor, esort);

    // 3) input projections via MFMA -> A1 x-slab (cols 0:128, stride 384)
    mfma_gemm_kernel<128, 128, 384, 128, false>
        <<<391, 512, 0, stream>>>(x0bf, wl0, lin0_b, A1, 50000);
    mfma_gemm_kernel<64, 128, 384, 128, false>
        <<<391, 512, 0, stream>>>(x1bf, wl1, lin1_b,
                                  A1 + (size_t)50000 * 384, 50000);

    // 4) layer 1: per-dst gather-mean into A1 agg slabs, then full-N GEMM+ReLU -> y1
    gather1_kernel<<<(N_NODES + 3) / 4, 256, 0, stream>>>(ptrb, esort, A1);
    mfma_gemm_kernel<384, 256, 256, 256, true>
        <<<782, 512, 0, stream>>>(A1, wc1, conv1_b, y1, N_NODES);

    // 5) layer 2: full-N GEMM y1 @ [root2|W0|W1] -> H (aliases A1), then combine -> zb
    mfma_gemm_kernel<256, 384, 384, 128, false>
        <<<782, 512, 0, stream>>>(y1, wc2, conv2_b, H, N_NODES);
    combine2_kernel<<<(N_NODES + 3) / 4, 256, 0, stream>>>(ptrb, esort, H, zb);

    // 6) decode
    decode_kernel<<<(N_PAIRS + 3) / 4, 256, 0, stream>>>(zb, dec_index, fc_w, fc_b, out);
}

// Round 8
// 274.291 us; speedup vs baseline: 1.0545x; 1.0545x over previous
//
#include <hip/hip_runtime.h>
#include <hip/hip_bf16.h>
#include <math.h>

#define N_NODES 100000
#define N_EDGES 400000
#define N_PAIRS 100000
#define NBINS   200000   // (rel, dst) bins

typedef short short8_t __attribute__((ext_vector_type(8)));
typedef float f32x4    __attribute__((ext_vector_type(4)));

__device__ __forceinline__ ushort f2bf(float f) {
    uint u = __float_as_uint(f);
    u += 0x7fffu + ((u >> 16) & 1u);          // RNE
    return (ushort)(u >> 16);
}
__device__ __forceinline__ float bf2f(ushort b) {
    return __uint_as_float(((uint)b) << 16);
}
__device__ __forceinline__ uint packbf(float a, float b) {
    return (uint)f2bf(a) | ((uint)f2bf(b) << 16);
}

#define GLDS16(gp, lp) \
    __builtin_amdgcn_global_load_lds((const __attribute__((address_space(1))) uint*)(gp), \
                                     (__attribute__((address_space(3))) uint*)(lp), 16, 0, 0)

template<int N> __device__ __forceinline__ void waitvm() {
    if constexpr (N == 0)      asm volatile("s_waitcnt vmcnt(0)" ::: "memory");
    else if constexpr (N == 4) asm volatile("s_waitcnt vmcnt(4)" ::: "memory");
    else if constexpr (N == 8) asm volatile("s_waitcnt vmcnt(8)" ::: "memory");
}

// ---------------------------------------------------------------------------
// fp32 -> bf16 cast (vectorized, grid-stride)
// ---------------------------------------------------------------------------
__global__ void cast_kernel(const float* __restrict__ in, ushort* __restrict__ outp, int n4) {
    int i = blockIdx.x * 256 + threadIdx.x;
    int stride = gridDim.x * 256;
    for (; i < n4; i += stride) {
        float4 v = ((const float4*)in)[i];
        ushort4 o;
        o.x = f2bf(v.x); o.y = f2bf(v.y); o.z = f2bf(v.z); o.w = f2bf(v.w);
        ((ushort4*)outp)[i] = o;
    }
}

// ---------------------------------------------------------------------------
// Weight repacks (bf16, K-major rows Wt[n][k])
// ---------------------------------------------------------------------------
__global__ void wlin_kernel(const float* __restrict__ w, ushort* __restrict__ wt, int K) {
    int i = blockIdx.x * 256 + threadIdx.x;    // 128*K
    if (i >= 128 * K) return;
    int n = i / K, k = i - n * K;
    wt[i] = f2bf(w[(size_t)k * 128 + n]);
}
__global__ void wc1_kernel(const float* __restrict__ root, const float* __restrict__ w,
                           ushort* __restrict__ wt) {
    int i = blockIdx.x * 256 + threadIdx.x;    // 256*384
    if (i >= 256 * 384) return;
    int n = i / 384, k = i % 384;
    float v;
    if (k < 128) v = root[(size_t)k * 256 + n];
    else         v = w[(size_t)(k - 128) * 256 + n];   // [2,128,256] contiguous
    wt[(size_t)n * 384 + k] = f2bf(v);
}
__global__ void wc2_kernel(const float* __restrict__ root, const float* __restrict__ w,
                           ushort* __restrict__ wt) {
    int i = blockIdx.x * 256 + threadIdx.x;    // 384*256
    if (i >= 384 * 256) return;
    int n = i / 256, k = i % 256;
    float v;
    if (n < 128) v = root[(size_t)k * 128 + n];
    else         v = w[((size_t)((n >> 7) - 1) * 256 + k) * 128 + (n & 127)];
    wt[(size_t)n * 256 + k] = f2bf(v);
}

// ---------------------------------------------------------------------------
// CSR build: histogram -> exclusive scan (3 kernels) -> fill
// ---------------------------------------------------------------------------
__global__ void hist_kernel(const int* __restrict__ dst, const int* __restrict__ et,
                            int* __restrict__ cnt) {
    int e = blockIdx.x * 256 + threadIdx.x;
    if (e < N_EDGES) atomicAdd(&cnt[et[e] * N_NODES + dst[e]], 1);
}

__global__ __launch_bounds__(1024) void scan1_kernel(const int* __restrict__ cnt,
                                                     int* __restrict__ ptr,
                                                     int* __restrict__ aux) {
    __shared__ int s[1024];
    int i = blockIdx.x * 1024 + threadIdx.x;
    int v = (i < NBINS) ? cnt[i] : 0;
    s[threadIdx.x] = v;
    __syncthreads();
    for (int off = 1; off < 1024; off <<= 1) {
        int t = (threadIdx.x >= off) ? s[threadIdx.x - off] : 0;
        __syncthreads();
        s[threadIdx.x] += t;
        __syncthreads();
    }
    if (i < NBINS) ptr[i] = s[threadIdx.x] - v;          // block-exclusive
    if (threadIdx.x == 1023) aux[blockIdx.x] = s[1023];  // block total
}

__global__ void scan2_kernel(int* __restrict__ aux, int nblk) {
    __shared__ int s[256];
    int v = (threadIdx.x < nblk) ? aux[threadIdx.x] : 0;
    s[threadIdx.x] = v;
    __syncthreads();
    for (int off = 1; off < 256; off <<= 1) {
        int t = (threadIdx.x >= off) ? s[threadIdx.x - off] : 0;
        __syncthreads();
        s[threadIdx.x] += t;
        __syncthreads();
    }
    if (threadIdx.x < nblk) aux[threadIdx.x] = s[threadIdx.x] - v;  // exclusive
}

__global__ void scan3_kernel(const int* __restrict__ aux, int* __restrict__ ptr,
                             int* __restrict__ cursor) {
    int i = blockIdx.x * 256 + threadIdx.x;
    if (i < NBINS) {
        int val = ptr[i] + aux[i >> 10];
        ptr[i] = val;
        cursor[i] = val;
    }
    if (i == 0) ptr[NBINS] = N_EDGES;
}

__global__ void fill_kernel(const int* __restrict__ src, const int* __restrict__ dst,
                            const int* __restrict__ et, int* __restrict__ cursor,
                            int* __restrict__ esorted) {
    int e = blockIdx.x * 256 + threadIdx.x;
    if (e < N_EDGES) {
        int b = et[e] * N_NODES + dst[e];
        int pos = atomicAdd(&cursor[b], 1);
        esorted[pos] = src[e];
    }
}

// ---------------------------------------------------------------------------
// Layer-1 gather-mean: one wave per dst node, both relations, unroll-2.
// ---------------------------------------------------------------------------
__global__ void gather1_kernel(const int* __restrict__ ptr, const int* __restrict__ es,
                               ushort* __restrict__ A1) {
    int d = blockIdx.x * 4 + (threadIdx.x >> 6);
    if (d >= N_NODES) return;
    int lane = threadIdx.x & 63;
    int p0 = ptr[d],           p1 = ptr[d + 1];
    int q0 = ptr[N_NODES + d], q1 = ptr[N_NODES + d + 1];
    int n0 = p1 - p0, n1 = q1 - q0;
    int n  = n0 > n1 ? n0 : n1;
    float a0 = 0, a1 = 0, b0 = 0, b1 = 0;
    for (int k = 0; k < n; k += 2) {
        uint v00 = 0, v01 = 0, v10 = 0, v11 = 0;
        if (k < n0)     v00 = *(const uint*)(A1 + (size_t)es[p0 + k] * 384 + lane * 2);
        if (k + 1 < n0) v01 = *(const uint*)(A1 + (size_t)es[p0 + k + 1] * 384 + lane * 2);
        if (k < n1)     v10 = *(const uint*)(A1 + (size_t)es[q0 + k] * 384 + lane * 2);
        if (k + 1 < n1) v11 = *(const uint*)(A1 + (size_t)es[q0 + k + 1] * 384 + lane * 2);
        a0 += bf2f((ushort)(v00 & 0xffffu)) + bf2f((ushort)(v01 & 0xffffu));
        a1 += bf2f((ushort)(v00 >> 16))     + bf2f((ushort)(v01 >> 16));
        b0 += bf2f((ushort)(v10 & 0xffffu)) + bf2f((ushort)(v11 & 0xffffu));
        b1 += bf2f((ushort)(v10 >> 16))     + bf2f((ushort)(v11 >> 16));
    }
    float i0 = n0 ? 1.0f / (float)n0 : 0.0f;
    float i1 = n1 ? 1.0f / (float)n1 : 0.0f;
    uint* row = (uint*)(A1 + (size_t)d * 384);
    row[64  + lane] = packbf(a0 * i0, a1 * i0);
    row[128 + lane] = packbf(b0 * i1, b1 * i1);
}

// ---------------------------------------------------------------------------
// Layer-2 combine: z[d] = H[d][0:128] + mean_r0 H[s][128:256] + mean_r1 H[s][256:384]
// One wave per dst node, unroll-2. z output bf16.
// ---------------------------------------------------------------------------
__global__ void combine2_kernel(const int* __restrict__ ptr, const int* __restrict__ es,
                                const ushort* __restrict__ H, ushort* __restrict__ zb) {
    int d = blockIdx.x * 4 + (threadIdx.x >> 6);
    if (d >= N_NODES) return;
    int lane = threadIdx.x & 63;
    int p0 = ptr[d],           p1 = ptr[d + 1];
    int q0 = ptr[N_NODES + d], q1 = ptr[N_NODES + d + 1];
    int n0 = p1 - p0, n1 = q1 - q0;
    int n  = n0 > n1 ? n0 : n1;
    uint rv = *(const uint*)(H + (size_t)d * 384 + lane * 2);
    float r0 = bf2f((ushort)(rv & 0xffffu)), r1 = bf2f((ushort)(rv >> 16));
    float a0 = 0, a1 = 0, b0 = 0, b1 = 0;
    for (int k = 0; k < n; k += 2) {
        uint v00 = 0, v01 = 0, v10 = 0, v11 = 0;
        if (k < n0)     v00 = *(const uint*)(H + (size_t)es[p0 + k] * 384 + 128 + lane * 2);
        if (k + 1 < n0) v01 = *(const uint*)(H + (size_t)es[p0 + k + 1] * 384 + 128 + lane * 2);
        if (k < n1)     v10 = *(const uint*)(H + (size_t)es[q0 + k] * 384 + 256 + lane * 2);
        if (k + 1 < n1) v11 = *(const uint*)(H + (size_t)es[q0 + k + 1] * 384 + 256 + lane * 2);
        a0 += bf2f((ushort)(v00 & 0xffffu)) + bf2f((ushort)(v01 & 0xffffu));
        a1 += bf2f((ushort)(v00 >> 16))     + bf2f((ushort)(v01 >> 16));
        b0 += bf2f((ushort)(v10 & 0xffffu)) + bf2f((ushort)(v11 & 0xffffu));
        b1 += bf2f((ushort)(v10 >> 16))     + bf2f((ushort)(v11 >> 16));
    }
    float i0 = n0 ? 1.0f / (float)n0 : 0.0f;
    float i1 = n1 ? 1.0f / (float)n1 : 0.0f;
    uint* orow = (uint*)(zb + (size_t)d * 128);
    orow[lane] = packbf(r0 + a0 * i0 + b0 * i1, r1 + a1 * i0 + b1 * i1);
}

// ---------------------------------------------------------------------------
// MFMA GEMM, 128x128 tile, 256 threads / 4 waves (2x2 quadrants), 3-slot
// LDS pipeline with counted vmcnt (prefetch distance 2 K-steps, never 0
// mid-loop), global_load_lds width-16, XOR-swizzled LDS (pre-swizzled global
// source + swizzled ds_read -> zero bank conflicts), XCD-bijective block
// swizzle (m204) with N-panel-fastest work order so all panels of an m-tile
// share one XCD's L2 (A-tile re-read becomes L2-hit).
// Grid: flat mtiles*NP blocks. out[row][n0+col] = A[row][:]@Wt[n0+col][:]
// (+bias if col<BIASN), optional ReLU, bf16 out with row stride OST.
// ---------------------------------------------------------------------------
template<int KTOT, int NP, int OST, int BIASN, bool RELU>
__global__ __launch_bounds__(256)
void mfma_gemm_kernel(const ushort* __restrict__ A, const ushort* __restrict__ Wt,
                      const float* __restrict__ bias, ushort* __restrict__ outp,
                      int nrows, int mtiles) {
    __shared__ short As[3][128 * 32];
    __shared__ short Bs[3][128 * 32];
    const int t = threadIdx.x;
    const int lane = t & 63, w = t >> 6;
    const int wr = w >> 1, wc = w & 1;
    const int l15 = lane & 15, l4 = lane >> 4;

    // XCD-bijective swizzle: XCD k (= orig%8) gets a contiguous work chunk.
    const int nwg = mtiles * NP;
    const int q = nwg >> 3, r = nwg & 7;
    const int orig = blockIdx.x;
    const int xcd = orig & 7;
    const int work = (xcd < r ? xcd * (q + 1) : r * (q + 1) + (xcd - r) * q) + (orig >> 3);
    const int mt = work / NP;
    const int m0 = mt * 128;
    const int n0 = (work - mt * NP) * 128;

    // staging: thread t owns chunks {t, t+256} of each 512x16B tile.
    // rows: arow and arow+64; same col swizzle for both ((row>>1)&3 invariant).
    const int arow = t >> 2;
    const int swc = ((t & 3) ^ ((arow >> 1) & 3)) * 8;
    int rg0 = m0 + arow;      if (rg0 >= nrows) rg0 = nrows - 1;
    int rg1 = m0 + arow + 64; if (rg1 >= nrows) rg1 = nrows - 1;
    const ushort* ap0 = A + (size_t)rg0 * KTOT + swc;
    const ushort* ap1 = A + (size_t)rg1 * KTOT + swc;
    const ushort* bp0 = Wt + (size_t)(n0 + arow) * KTOT + swc;
    const ushort* bp1 = Wt + (size_t)(n0 + arow + 64) * KTOT + swc;

#define STAGE(slot, kg) do { \
        GLDS16(ap0 + (kg), &As[slot][t * 8]); \
        GLDS16(ap1 + (kg), &As[slot][(t + 256) * 8]); \
        GLDS16(bp0 + (kg), &Bs[slot][t * 8]); \
        GLDS16(bp1 + (kg), &Bs[slot][(t + 256) * 8]); \
    } while (0)

    f32x4 acc[4][4];
#pragma unroll
    for (int j = 0; j < 4; j++) {
        int col = n0 + wc * 64 + j * 16 + l15;
        float bv = (col < BIASN) ? bias[col] : 0.0f;
        f32x4 tmp = {bv, bv, bv, bv};
#pragma unroll
        for (int i = 0; i < 4; i++) acc[i][j] = tmp;
    }

    // read-side swizzle: logical chunk l4 stored at l4^((row>>1)&3), and
    // (row>>1)&3 == (l15>>1)&3 for all fragment rows (bases multiple of 8).
    const int xr = (l4 ^ ((l15 >> 1) & 3)) * 8;

    constexpr int NSTEP = KTOT / 32;
    STAGE(0, 0);
    if (NSTEP > 1) STAGE(1, 32);
    for (int ks = 0; ks < NSTEP; ks++) {
        const int slot = ks % 3;
        if (ks + 2 < NSTEP) {
            STAGE((ks + 2) % 3, (ks + 2) * 32);
            waitvm<8>();                           // slot ks done; 2 slots in flight
        } else if (ks + 1 < NSTEP) {
            waitvm<4>();
        } else {
            waitvm<0>();
        }
        asm volatile("s_barrier" ::: "memory");    // slot staged for all waves
        short8_t af[4], bfr[4];
#pragma unroll
        for (int i = 0; i < 4; i++)
            af[i] = *(short8_t*)&As[slot][(wr * 64 + i * 16 + l15) * 32 + xr];
#pragma unroll
        for (int j = 0; j < 4; j++)
            bfr[j] = *(short8_t*)&Bs[slot][(wc * 64 + j * 16 + l15) * 32 + xr];
#pragma unroll
        for (int i = 0; i < 4; i++)
#pragma unroll
            for (int j = 0; j < 4; j++)
                acc[i][j] = __builtin_amdgcn_mfma_f32_16x16x32_bf16(af[i], bfr[j], acc[i][j], 0, 0, 0);
        asm volatile("s_barrier" ::: "memory");    // reads done before slot re-stage
    }
#undef STAGE

#pragma unroll
    for (int i = 0; i < 4; i++) {
#pragma unroll
        for (int r2 = 0; r2 < 4; r2++) {
            int row = m0 + wr * 64 + i * 16 + l4 * 4 + r2;
            if (row < nrows) {
#pragma unroll
                for (int j = 0; j < 4; j++) {
                    int col = n0 + wc * 64 + j * 16 + l15;
                    float v = acc[i][j][r2];
                    if (RELU) v = fmaxf(v, 0.0f);
                    outp[(size_t)row * OST + col] = f2bf(v);
                }
            }
        }
    }
}

// ---------------------------------------------------------------------------
// Decode: out[p] = sigmoid( z[s]·fcw[0:128] + z[d]·fcw[128:256] + fcb ), z bf16
// ---------------------------------------------------------------------------
__global__ void decode_kernel(const ushort* __restrict__ zb, const int* __restrict__ dec,
                              const float* __restrict__ fcw, const float* __restrict__ fcb,
                              float* __restrict__ out) {
    int wid  = blockIdx.x * 4 + (threadIdx.x >> 6);
    int lane = threadIdx.x & 63;
    if (wid >= N_PAIRS) return;
    int s = dec[wid];
    int d = dec[N_PAIRS + wid];
    uint vs = ((const uint*)(zb + (size_t)s * 128))[lane];
    uint vd = ((const uint*)(zb + (size_t)d * 128))[lane];
    float v = bf2f((ushort)(vs & 0xffffu)) * fcw[2 * lane]
            + bf2f((ushort)(vs >> 16))     * fcw[2 * lane + 1]
            + bf2f((ushort)(vd & 0xffffu)) * fcw[128 + 2 * lane]
            + bf2f((ushort)(vd >> 16))     * fcw[128 + 2 * lane + 1];
#pragma unroll
    for (int off = 32; off > 0; off >>= 1) v += __shfl_down(v, off);
    if (lane == 0) out[wid] = 1.0f / (1.0f + expf(-(v + fcb[0])));
}

// ---------------------------------------------------------------------------
extern "C" void kernel_launch(void* const* d_in, const int* in_sizes, int n_in,
                              void* d_out, int out_size, void* d_ws, size_t ws_size,
                              hipStream_t stream) {
    const float* x0        = (const float*)d_in[0];
    const float* x1        = (const float*)d_in[1];
    const int*   edge_idx  = (const int*)  d_in[2];
    const int*   edge_type = (const int*)  d_in[3];
    const int*   dec_index = (const int*)  d_in[4];
    const float* lin0_w    = (const float*)d_in[5];
    const float* lin0_b    = (const float*)d_in[6];
    const float* lin1_w    = (const float*)d_in[7];
    const float* lin1_b    = (const float*)d_in[8];
    const float* conv1_w   = (const float*)d_in[9];
    const float* conv1_root= (const float*)d_in[10];
    const float* conv1_b   = (const float*)d_in[11];
    const float* conv2_w   = (const float*)d_in[12];
    const float* conv2_root= (const float*)d_in[13];
    const float* conv2_b   = (const float*)d_in[14];
    const float* fc_w      = (const float*)d_in[15];
    const float* fc_b      = (const float*)d_in[16];
    float* out = (float*)d_out;

    // ---- workspace layout (bytes), ~151.6 MB; H aliases A1, zb aliases y1 ----
    char* W = (char*)d_ws;
    ushort* A1    = (ushort*)(W + 0);            // 76,800,000 B [100k][384] = [x|agg0|agg1]
    ushort* H     = (ushort*)(W + 0);            // alias (A1 dead after gemm1)
    ushort* y1    = (ushort*)(W + 76800000);     // 51,200,000 B [100k][256]
    ushort* zb    = (ushort*)(W + 76800000);     // alias: [100k][128] bf16 (y1 dead after gemm2)
    int*    cnt   = (int*)   (W + 128000000);
    int*    ptrb  = (int*)   (W + 128800000);
    int*    cursor= (int*)   (W + 129600016);
    int*    aux   = (int*)   (W + 130400016);
    int*    esort = (int*)   (W + 130404112);
    ushort* wc1   = (ushort*)(W + 132004112);    // [256][384] bf16
    ushort* wc2   = (ushort*)(W + 132200720);    // [384][256] bf16
    ushort* wl0   = (ushort*)(W + 132397328);    // [128][128] bf16
    ushort* wl1   = (ushort*)(W + 132430096);    // [128][64]  bf16
    ushort* x0bf  = (ushort*)(W + 132446480);    // [50000][128] bf16
    ushort* x1bf  = (ushort*)(W + 145246480);    // [50000][64]  bf16

    const int* esrc = edge_idx;
    const int* edst = edge_idx + N_EDGES;

    // 0) zero histogram
    hipMemsetAsync(cnt, 0, (size_t)NBINS * sizeof(int), stream);

    // 1) casts + weight repacks
    cast_kernel<<<2048, 256, 0, stream>>>(x0, x0bf, 50000 * 128 / 4);
    cast_kernel<<<2048, 256, 0, stream>>>(x1, x1bf, 50000 * 64 / 4);
    wlin_kernel<<<64, 256, 0, stream>>>(lin0_w, wl0, 128);
    wlin_kernel<<<32, 256, 0, stream>>>(lin1_w, wl1, 64);
    wc1_kernel<<<(256 * 384 + 255) / 256, 256, 0, stream>>>(conv1_root, conv1_w, wc1);
    wc2_kernel<<<(384 * 256 + 255) / 256, 256, 0, stream>>>(conv2_root, conv2_w, wc2);

    // 2) CSR build over (rel,dst)
    hist_kernel<<<(N_EDGES + 255) / 256, 256, 0, stream>>>(edst, edge_type, cnt);
    scan1_kernel<<<(NBINS + 1023) / 1024, 1024, 0, stream>>>(cnt, ptrb, aux);
    scan2_kernel<<<1, 256, 0, stream>>>(aux, (NBINS + 1023) / 1024);
    scan3_kernel<<<(NBINS + 255) / 256, 256, 0, stream>>>(aux, ptrb, cursor);
    fill_kernel<<<(N_EDGES + 255) / 256, 256, 0, stream>>>(esrc, edst, edge_type,
                                                           cursor, esort);

    // 3) input projections via MFMA -> A1 x-slab (cols 0:128, stride 384)
    mfma_gemm_kernel<128, 1, 384, 128, false>
        <<<391, 256, 0, stream>>>(x0bf, wl0, lin0_b, A1, 50000, 391);
    mfma_gemm_kernel<64, 1, 384, 128, false>
        <<<391, 256, 0, stream>>>(x1bf, wl1, lin1_b,
                                  A1 + (size_t)50000 * 384, 50000, 391);

    // 4) layer 1: per-dst gather-mean into A1 agg slabs, then GEMM+ReLU -> y1
    gather1_kernel<<<(N_NODES + 3) / 4, 256, 0, stream>>>(ptrb, esort, A1);
    mfma_gemm_kernel<384, 2, 256, 256, true>
        <<<1564, 256, 0, stream>>>(A1, wc1, conv1_b, y1, N_NODES, 782);

    // 5) layer 2: GEMM y1 @ [root2|W0|W1] -> H (aliases A1), then combine -> zb
    mfma_gemm_kernel<256, 3, 384, 128, false>
        <<<2346, 256, 0, stream>>>(y1, wc2, conv2_b, H, N_NODES, 782);
    combine2_kernel<<<(N_NODES + 3) / 4, 256, 0, stream>>>(ptrb, esort, H, zb);

    // 6) decode
    decode_kernel<<<(N_PAIRS + 3) / 4, 256, 0, stream>>>(zb, dec_index, fc_w, fc_b, out);
}

// Round 10
// 257.412 us; speedup vs baseline: 1.1237x; 1.0656x over previous
//
#include <hip/hip_runtime.h>
#include <hip/hip_bf16.h>
#include <math.h>

#define N_NODES 100000
#define N_EDGES 400000
#define N_PAIRS 100000
#define NBINS   200000   // (rel, dst) bins

typedef short short8_t __attribute__((ext_vector_type(8)));
typedef float f32x4    __attribute__((ext_vector_type(4)));

__device__ __forceinline__ ushort f2bf(float f) {
    uint u = __float_as_uint(f);
    u += 0x7fffu + ((u >> 16) & 1u);          // RNE
    return (ushort)(u >> 16);
}
__device__ __forceinline__ float bf2f(ushort b) {
    return __uint_as_float(((uint)b) << 16);
}
__device__ __forceinline__ uint packbf(float a, float b) {
    return (uint)f2bf(a) | ((uint)f2bf(b) << 16);
}

#define GLDS16(gp, lp) \
    __builtin_amdgcn_global_load_lds((const __attribute__((address_space(1))) uint*)(gp), \
                                     (__attribute__((address_space(3))) uint*)(lp), 16, 0, 0)

template<int N> __device__ __forceinline__ void waitvm() {
    if constexpr (N == 0)      asm volatile("s_waitcnt vmcnt(0)" ::: "memory");
    else if constexpr (N == 4) asm volatile("s_waitcnt vmcnt(4)" ::: "memory");
    else if constexpr (N == 8) asm volatile("s_waitcnt vmcnt(8)" ::: "memory");
}

// ---------------------------------------------------------------------------
// prep: fuses x0/x1 bf16 casts, the 4 weight repacks, and cnt zeroing.
// Work regions (grid-stride over TOTAL items):
//   r0: 1,600,000  x0 cast (float4)        r1: 800,000  x1 cast (float4)
//   r2: 16,384     wl0                     r3: 8,192    wl1
//   r4: 98,304     wc1                     r5: 98,304   wc2
//   r6: 50,000     cnt zero (int4)
// ---------------------------------------------------------------------------
#define PREP_TOTAL 2671184
__global__ void prep_kernel(const float* __restrict__ x0, const float* __restrict__ x1,
                            const float* __restrict__ l0w, const float* __restrict__ l1w,
                            const float* __restrict__ c1r, const float* __restrict__ c1w,
                            const float* __restrict__ c2r, const float* __restrict__ c2w,
                            ushort* __restrict__ x0bf, ushort* __restrict__ x1bf,
                            ushort* __restrict__ wl0, ushort* __restrict__ wl1,
                            ushort* __restrict__ wc1, ushort* __restrict__ wc2,
                            int* __restrict__ cnt) {
    int i = blockIdx.x * 256 + threadIdx.x;
    const int stride = gridDim.x * 256;
    for (; i < PREP_TOTAL; i += stride) {
        int j = i;
        if (j < 1600000) {
            float4 v = ((const float4*)x0)[j];
            ushort4 o; o.x = f2bf(v.x); o.y = f2bf(v.y); o.z = f2bf(v.z); o.w = f2bf(v.w);
            ((ushort4*)x0bf)[j] = o;
        } else if ((j -= 1600000) < 800000) {
            float4 v = ((const float4*)x1)[j];
            ushort4 o; o.x = f2bf(v.x); o.y = f2bf(v.y); o.z = f2bf(v.z); o.w = f2bf(v.w);
            ((ushort4*)x1bf)[j] = o;
        } else if ((j -= 800000) < 16384) {
            int n = j >> 7, k = j & 127;
            wl0[j] = f2bf(l0w[(size_t)k * 128 + n]);
        } else if ((j -= 16384) < 8192) {
            int n = j >> 6, k = j & 63;
            wl1[j] = f2bf(l1w[(size_t)k * 128 + n]);
        } else if ((j -= 8192) < 98304) {
            int n = j / 384, k = j % 384;
            float v = (k < 128) ? c1r[(size_t)k * 256 + n] : c1w[(size_t)(k - 128) * 256 + n];
            wc1[(size_t)n * 384 + k] = f2bf(v);
        } else if ((j -= 98304) < 98304) {
            int n = j >> 8, k = j & 255;
            float v = (n < 128) ? c2r[(size_t)k * 128 + n]
                                : c2w[((size_t)((n >> 7) - 1) * 256 + k) * 128 + (n & 127)];
            wc2[(size_t)n * 256 + k] = f2bf(v);
        } else {
            j -= 98304;
            ((int4*)cnt)[j] = make_int4(0, 0, 0, 0);
        }
    }
}

// ---------------------------------------------------------------------------
// CSR build: histogram -> exclusive scan (3 kernels) -> fill
// ---------------------------------------------------------------------------
__global__ void hist_kernel(const int* __restrict__ dst, const int* __restrict__ et,
                            int* __restrict__ cnt) {
    int e = blockIdx.x * 256 + threadIdx.x;
    if (e < N_EDGES) atomicAdd(&cnt[et[e] * N_NODES + dst[e]], 1);
}

__global__ __launch_bounds__(1024) void scan1_kernel(const int* __restrict__ cnt,
                                                     int* __restrict__ ptr,
                                                     int* __restrict__ aux) {
    __shared__ int s[1024];
    int i = blockIdx.x * 1024 + threadIdx.x;
    int v = (i < NBINS) ? cnt[i] : 0;
    s[threadIdx.x] = v;
    __syncthreads();
    for (int off = 1; off < 1024; off <<= 1) {
        int t = (threadIdx.x >= off) ? s[threadIdx.x - off] : 0;
        __syncthreads();
        s[threadIdx.x] += t;
        __syncthreads();
    }
    if (i < NBINS) ptr[i] = s[threadIdx.x] - v;          // block-exclusive
    if (threadIdx.x == 1023) aux[blockIdx.x] = s[1023];  // block total
}

__global__ void scan2_kernel(int* __restrict__ aux, int nblk) {
    __shared__ int s[256];
    int v = (threadIdx.x < nblk) ? aux[threadIdx.x] : 0;
    s[threadIdx.x] = v;
    __syncthreads();
    for (int off = 1; off < 256; off <<= 1) {
        int t = (threadIdx.x >= off) ? s[threadIdx.x - off] : 0;
        __syncthreads();
        s[threadIdx.x] += t;
        __syncthreads();
    }
    if (threadIdx.x < nblk) aux[threadIdx.x] = s[threadIdx.x] - v;  // exclusive
}

__global__ void scan3_kernel(const int* __restrict__ aux, int* __restrict__ ptr,
                             int* __restrict__ cursor) {
    int i = blockIdx.x * 256 + threadIdx.x;
    if (i < NBINS) {
        int val = ptr[i] + aux[i >> 10];
        ptr[i] = val;
        cursor[i] = val;
    }
    if (i == 0) ptr[NBINS] = N_EDGES;
}

__global__ void fill_kernel(const int* __restrict__ src, const int* __restrict__ dst,
                            const int* __restrict__ et, int* __restrict__ cursor,
                            int* __restrict__ esorted) {
    int e = blockIdx.x * 256 + threadIdx.x;
    if (e < N_EDGES) {
        int b = et[e] * N_NODES + dst[e];
        int pos = atomicAdd(&cursor[b], 1);
        esorted[pos] = src[e];
    }
}

// ---------------------------------------------------------------------------
// Layer-1 gather-mean (round-8 proven structure, unroll-4): one full wave per
// dst node, both relations, uint/lane row reads, 8 loads in flight.
// ---------------------------------------------------------------------------
__global__ void gather1_kernel(const int* __restrict__ ptr, const int* __restrict__ es,
                               ushort* __restrict__ A1) {
    int d = blockIdx.x * 4 + (threadIdx.x >> 6);
    if (d >= N_NODES) return;
    int lane = threadIdx.x & 63;
    int p0 = ptr[d],           p1 = ptr[d + 1];
    int q0 = ptr[N_NODES + d], q1 = ptr[N_NODES + d + 1];
    int n0 = p1 - p0, n1 = q1 - q0;
    int n  = n0 > n1 ? n0 : n1;
    float a0 = 0, a1 = 0, b0 = 0, b1 = 0;
    for (int k = 0; k < n; k += 4) {
        uint v00 = 0, v01 = 0, v02 = 0, v03 = 0;
        uint v10 = 0, v11 = 0, v12 = 0, v13 = 0;
        if (k     < n0) v00 = *(const uint*)(A1 + (size_t)es[p0 + k]     * 384 + lane * 2);
        if (k + 1 < n0) v01 = *(const uint*)(A1 + (size_t)es[p0 + k + 1] * 384 + lane * 2);
        if (k + 2 < n0) v02 = *(const uint*)(A1 + (size_t)es[p0 + k + 2] * 384 + lane * 2);
        if (k + 3 < n0) v03 = *(const uint*)(A1 + (size_t)es[p0 + k + 3] * 384 + lane * 2);
        if (k     < n1) v10 = *(const uint*)(A1 + (size_t)es[q0 + k]     * 384 + lane * 2);
        if (k + 1 < n1) v11 = *(const uint*)(A1 + (size_t)es[q0 + k + 1] * 384 + lane * 2);
        if (k + 2 < n1) v12 = *(const uint*)(A1 + (size_t)es[q0 + k + 2] * 384 + lane * 2);
        if (k + 3 < n1) v13 = *(const uint*)(A1 + (size_t)es[q0 + k + 3] * 384 + lane * 2);
        a0 += bf2f((ushort)(v00 & 0xffffu)) + bf2f((ushort)(v01 & 0xffffu))
            + bf2f((ushort)(v02 & 0xffffu)) + bf2f((ushort)(v03 & 0xffffu));
        a1 += bf2f((ushort)(v00 >> 16)) + bf2f((ushort)(v01 >> 16))
            + bf2f((ushort)(v02 >> 16)) + bf2f((ushort)(v03 >> 16));
        b0 += bf2f((ushort)(v10 & 0xffffu)) + bf2f((ushort)(v11 & 0xffffu))
            + bf2f((ushort)(v12 & 0xffffu)) + bf2f((ushort)(v13 & 0xffffu));
        b1 += bf2f((ushort)(v10 >> 16)) + bf2f((ushort)(v11 >> 16))
            + bf2f((ushort)(v12 >> 16)) + bf2f((ushort)(v13 >> 16));
    }
    float i0 = n0 ? 1.0f / (float)n0 : 0.0f;
    float i1 = n1 ? 1.0f / (float)n1 : 0.0f;
    uint* row = (uint*)(A1 + (size_t)d * 384);
    row[64  + lane] = packbf(a0 * i0, a1 * i0);
    row[128 + lane] = packbf(b0 * i1, b1 * i1);
}

// ---------------------------------------------------------------------------
// Layer-2 combine (round-8 proven structure, unroll-4):
// z[d] = H[d][0:128] + mean_r0 H[s][128:256] + mean_r1 H[s][256:384], bf16 out.
// ---------------------------------------------------------------------------
__global__ void combine2_kernel(const int* __restrict__ ptr, const int* __restrict__ es,
                                const ushort* __restrict__ H, ushort* __restrict__ zb) {
    int d = blockIdx.x * 4 + (threadIdx.x >> 6);
    if (d >= N_NODES) return;
    int lane = threadIdx.x & 63;
    int p0 = ptr[d],           p1 = ptr[d + 1];
    int q0 = ptr[N_NODES + d], q1 = ptr[N_NODES + d + 1];
    int n0 = p1 - p0, n1 = q1 - q0;
    int n  = n0 > n1 ? n0 : n1;
    uint rv = *(const uint*)(H + (size_t)d * 384 + lane * 2);
    float r0 = bf2f((ushort)(rv & 0xffffu)), r1 = bf2f((ushort)(rv >> 16));
    float a0 = 0, a1 = 0, b0 = 0, b1 = 0;
    for (int k = 0; k < n; k += 4) {
        uint v00 = 0, v01 = 0, v02 = 0, v03 = 0;
        uint v10 = 0, v11 = 0, v12 = 0, v13 = 0;
        if (k     < n0) v00 = *(const uint*)(H + (size_t)es[p0 + k]     * 384 + 128 + lane * 2);
        if (k + 1 < n0) v01 = *(const uint*)(H + (size_t)es[p0 + k + 1] * 384 + 128 + lane * 2);
        if (k + 2 < n0) v02 = *(const uint*)(H + (size_t)es[p0 + k + 2] * 384 + 128 + lane * 2);
        if (k + 3 < n0) v03 = *(const uint*)(H + (size_t)es[p0 + k + 3] * 384 + 128 + lane * 2);
        if (k     < n1) v10 = *(const uint*)(H + (size_t)es[q0 + k]     * 384 + 256 + lane * 2);
        if (k + 1 < n1) v11 = *(const uint*)(H + (size_t)es[q0 + k + 1] * 384 + 256 + lane * 2);
        if (k + 2 < n1) v12 = *(const uint*)(H + (size_t)es[q0 + k + 2] * 384 + 256 + lane * 2);
        if (k + 3 < n1) v13 = *(const uint*)(H + (size_t)es[q0 + k + 3] * 384 + 256 + lane * 2);
        a0 += bf2f((ushort)(v00 & 0xffffu)) + bf2f((ushort)(v01 & 0xffffu))
            + bf2f((ushort)(v02 & 0xffffu)) + bf2f((ushort)(v03 & 0xffffu));
        a1 += bf2f((ushort)(v00 >> 16)) + bf2f((ushort)(v01 >> 16))
            + bf2f((ushort)(v02 >> 16)) + bf2f((ushort)(v03 >> 16));
        b0 += bf2f((ushort)(v10 & 0xffffu)) + bf2f((ushort)(v11 & 0xffffu))
            + bf2f((ushort)(v12 & 0xffffu)) + bf2f((ushort)(v13 & 0xffffu));
        b1 += bf2f((ushort)(v10 >> 16)) + bf2f((ushort)(v11 >> 16))
            + bf2f((ushort)(v12 >> 16)) + bf2f((ushort)(v13 >> 16));
    }
    float i0 = n0 ? 1.0f / (float)n0 : 0.0f;
    float i1 = n1 ? 1.0f / (float)n1 : 0.0f;
    uint* orow = (uint*)(zb + (size_t)d * 128);
    orow[lane] = packbf(r0 + a0 * i0 + b0 * i1, r1 + a1 * i0 + b1 * i1);
}

// ---------------------------------------------------------------------------
// MFMA GEMM body: 128x128 tile, 256 threads / 4 waves (2x2 quadrants), 3-slot
// LDS pipeline with counted vmcnt, global_load_lds width-16, XOR-swizzled LDS.
// ---------------------------------------------------------------------------
template<int KTOT, int OST, int BIASN, bool RELU>
__device__ __forceinline__
void gemm_body(const ushort* __restrict__ A, const ushort* __restrict__ Wt,
               const float* __restrict__ bias, ushort* __restrict__ outp,
               int nrows, int m0, int n0) {
    __shared__ short As[3][128 * 32];
    __shared__ short Bs[3][128 * 32];
    const int t = threadIdx.x;
    const int lane = t & 63, w = t >> 6;
    const int wr = w >> 1, wc = w & 1;
    const int l15 = lane & 15, l4 = lane >> 4;

    const int arow = t >> 2;
    const int swc = ((t & 3) ^ ((arow >> 1) & 3)) * 8;
    int rg0 = m0 + arow;      if (rg0 >= nrows) rg0 = nrows - 1;
    int rg1 = m0 + arow + 64; if (rg1 >= nrows) rg1 = nrows - 1;
    const ushort* ap0 = A + (size_t)rg0 * KTOT + swc;
    const ushort* ap1 = A + (size_t)rg1 * KTOT + swc;
    const ushort* bp0 = Wt + (size_t)(n0 + arow) * KTOT + swc;
    const ushort* bp1 = Wt + (size_t)(n0 + arow + 64) * KTOT + swc;

#define STAGE(slot, kg) do { \
        GLDS16(ap0 + (kg), &As[slot][t * 8]); \
        GLDS16(ap1 + (kg), &As[slot][(t + 256) * 8]); \
        GLDS16(bp0 + (kg), &Bs[slot][t * 8]); \
        GLDS16(bp1 + (kg), &Bs[slot][(t + 256) * 8]); \
    } while (0)

    f32x4 acc[4][4];
#pragma unroll
    for (int j = 0; j < 4; j++) {
        int col = n0 + wc * 64 + j * 16 + l15;
        float bv = (col < BIASN) ? bias[col] : 0.0f;
        f32x4 tmp = {bv, bv, bv, bv};
#pragma unroll
        for (int i = 0; i < 4; i++) acc[i][j] = tmp;
    }

    const int xr = (l4 ^ ((l15 >> 1) & 3)) * 8;

    constexpr int NSTEP = KTOT / 32;
    STAGE(0, 0);
    if (NSTEP > 1) STAGE(1, 32);
    for (int ks = 0; ks < NSTEP; ks++) {
        const int slot = ks % 3;
        if (ks + 2 < NSTEP) {
            STAGE((ks + 2) % 3, (ks + 2) * 32);
            waitvm<8>();
        } else if (ks + 1 < NSTEP) {
            waitvm<4>();
        } else {
            waitvm<0>();
        }
        asm volatile("s_barrier" ::: "memory");
        short8_t af[4], bfr[4];
#pragma unroll
        for (int i = 0; i < 4; i++)
            af[i] = *(short8_t*)&As[slot][(wr * 64 + i * 16 + l15) * 32 + xr];
#pragma unroll
        for (int j = 0; j < 4; j++)
            bfr[j] = *(short8_t*)&Bs[slot][(wc * 64 + j * 16 + l15) * 32 + xr];
#pragma unroll
        for (int i = 0; i < 4; i++)
#pragma unroll
            for (int j = 0; j < 4; j++)
                acc[i][j] = __builtin_amdgcn_mfma_f32_16x16x32_bf16(af[i], bfr[j], acc[i][j], 0, 0, 0);
        asm volatile("s_barrier" ::: "memory");
    }
#undef STAGE

#pragma unroll
    for (int i = 0; i < 4; i++) {
#pragma unroll
        for (int r2 = 0; r2 < 4; r2++) {
            int row = m0 + wr * 64 + i * 16 + l4 * 4 + r2;
            if (row < nrows) {
#pragma unroll
                for (int j = 0; j < 4; j++) {
                    int col = n0 + wc * 64 + j * 16 + l15;
                    float v = acc[i][j][r2];
                    if (RELU) v = fmaxf(v, 0.0f);
                    outp[(size_t)row * OST + col] = f2bf(v);
                }
            }
        }
    }
}

// GEMM wrapper with XCD-bijective swizzle + N-panel-fastest order.
template<int KTOT, int NP, int OST, int BIASN, bool RELU>
__global__ __launch_bounds__(256)
void mfma_gemm_kernel(const ushort* __restrict__ A, const ushort* __restrict__ Wt,
                      const float* __restrict__ bias, ushort* __restrict__ outp,
                      int nrows, int mtiles) {
    const int nwg = mtiles * NP;
    const int q = nwg >> 3, r = nwg & 7;
    const int orig = blockIdx.x;
    const int xcd = orig & 7;
    const int work = (xcd < r ? xcd * (q + 1) : r * (q + 1) + (xcd - r) * q) + (orig >> 3);
    const int mt = work / NP;
    gemm_body<KTOT, OST, BIASN, RELU>(A, Wt, bias, outp, nrows,
                                      mt * 128, (work - mt * NP) * 128);
}

// Both input projections in one launch: blocks [0,391) type0 (K=128),
// [391,782) type1 (K=64). Output into A1 x-slab (stride 384).
__global__ __launch_bounds__(256)
void proj_kernel(const ushort* __restrict__ x0bf, const ushort* __restrict__ x1bf,
                 const ushort* __restrict__ wl0, const ushort* __restrict__ wl1,
                 const float* __restrict__ l0b, const float* __restrict__ l1b,
                 ushort* __restrict__ A1) {
    if (blockIdx.x < 391)
        gemm_body<128, 384, 128, false>(x0bf, wl0, l0b, A1, 50000,
                                        blockIdx.x * 128, 0);
    else
        gemm_body<64, 384, 128, false>(x1bf, wl1, l1b, A1 + (size_t)50000 * 384, 50000,
                                       (blockIdx.x - 391) * 128, 0);
}

// ---------------------------------------------------------------------------
// Decode (round-8 proven): out[p] = sigmoid(z[s]·fcw[0:128]+z[d]·fcw[128:256]+fcb)
// ---------------------------------------------------------------------------
__global__ void decode_kernel(const ushort* __restrict__ zb, const int* __restrict__ dec,
                              const float* __restrict__ fcw, const float* __restrict__ fcb,
                              float* __restrict__ out) {
    int wid  = blockIdx.x * 4 + (threadIdx.x >> 6);
    int lane = threadIdx.x & 63;
    if (wid >= N_PAIRS) return;
    int s = dec[wid];
    int d = dec[N_PAIRS + wid];
    uint vs = ((const uint*)(zb + (size_t)s * 128))[lane];
    uint vd = ((const uint*)(zb + (size_t)d * 128))[lane];
    float v = bf2f((ushort)(vs & 0xffffu)) * fcw[2 * lane]
            + bf2f((ushort)(vs >> 16))     * fcw[2 * lane + 1]
            + bf2f((ushort)(vd & 0xffffu)) * fcw[128 + 2 * lane]
            + bf2f((ushort)(vd >> 16))     * fcw[128 + 2 * lane + 1];
#pragma unroll
    for (int off = 32; off > 0; off >>= 1) v += __shfl_down(v, off);
    if (lane == 0) out[wid] = 1.0f / (1.0f + expf(-(v + fcb[0])));
}

// ---------------------------------------------------------------------------
extern "C" void kernel_launch(void* const* d_in, const int* in_sizes, int n_in,
                              void* d_out, int out_size, void* d_ws, size_t ws_size,
                              hipStream_t stream) {
    const float* x0        = (const float*)d_in[0];
    const float* x1        = (const float*)d_in[1];
    const int*   edge_idx  = (const int*)  d_in[2];
    const int*   edge_type = (const int*)  d_in[3];
    const int*   dec_index = (const int*)  d_in[4];
    const float* lin0_w    = (const float*)d_in[5];
    const float* lin0_b    = (const float*)d_in[6];
    const float* lin1_w    = (const float*)d_in[7];
    const float* lin1_b    = (const float*)d_in[8];
    const float* conv1_w   = (const float*)d_in[9];
    const float* conv1_root= (const float*)d_in[10];
    const float* conv1_b   = (const float*)d_in[11];
    const float* conv2_w   = (const float*)d_in[12];
    const float* conv2_root= (const float*)d_in[13];
    const float* conv2_b   = (const float*)d_in[14];
    const float* fc_w      = (const float*)d_in[15];
    const float* fc_b      = (const float*)d_in[16];
    float* out = (float*)d_out;

    // ---- workspace layout (bytes), ~151.6 MB; H aliases A1, zb aliases y1 ----
    char* W = (char*)d_ws;
    ushort* A1    = (ushort*)(W + 0);            // 76,800,000 B [100k][384] = [x|agg0|agg1]
    ushort* H     = (ushort*)(W + 0);            // alias (A1 dead after gemm1)
    ushort* y1    = (ushort*)(W + 76800000);     // 51,200,000 B [100k][256]
    ushort* zb    = (ushort*)(W + 76800000);     // alias: [100k][128] bf16 (y1 dead after gemm2)
    int*    cnt   = (int*)   (W + 128000000);
    int*    ptrb  = (int*)   (W + 128800000);
    int*    cursor= (int*)   (W + 129600016);
    int*    aux   = (int*)   (W + 130400016);
    int*    esort = (int*)   (W + 130404112);
    ushort* wc1   = (ushort*)(W + 132004112);    // [256][384] bf16
    ushort* wc2   = (ushort*)(W + 132200720);    // [384][256] bf16
    ushort* wl0   = (ushort*)(W + 132397328);    // [128][128] bf16
    ushort* wl1   = (ushort*)(W + 132430096);    // [128][64]  bf16
    ushort* x0bf  = (ushort*)(W + 132446480);    // [50000][128] bf16
    ushort* x1bf  = (ushort*)(W + 145246480);    // [50000][64]  bf16

    const int* esrc = edge_idx;
    const int* edst = edge_idx + N_EDGES;

    // 1) fused prep: casts, weight repacks, cnt zero
    prep_kernel<<<2048, 256, 0, stream>>>(x0, x1, lin0_w, lin1_w,
                                          conv1_root, conv1_w, conv2_root, conv2_w,
                                          x0bf, x1bf, wl0, wl1, wc1, wc2, cnt);

    // 2) CSR build over (rel,dst)
    hist_kernel<<<(N_EDGES + 255) / 256, 256, 0, stream>>>(edst, edge_type, cnt);
    scan1_kernel<<<(NBINS + 1023) / 1024, 1024, 0, stream>>>(cnt, ptrb, aux);
    scan2_kernel<<<1, 256, 0, stream>>>(aux, (NBINS + 1023) / 1024);
    scan3_kernel<<<(NBINS + 255) / 256, 256, 0, stream>>>(aux, ptrb, cursor);
    fill_kernel<<<(N_EDGES + 255) / 256, 256, 0, stream>>>(esrc, edst, edge_type,
                                                           cursor, esort);

    // 3) both input projections -> A1 x-slab (cols 0:128, stride 384)
    proj_kernel<<<782, 256, 0, stream>>>(x0bf, x1bf, wl0, wl1, lin0_b, lin1_b, A1);

    // 4) layer 1: per-dst gather-mean into A1 agg slabs, then GEMM+ReLU -> y1
    gather1_kernel<<<(N_NODES + 3) / 4, 256, 0, stream>>>(ptrb, esort, A1);
    mfma_gemm_kernel<384, 2, 256, 256, true>
        <<<1564, 256, 0, stream>>>(A1, wc1, conv1_b, y1, N_NODES, 782);

    // 5) layer 2: GEMM y1 @ [root2|W0|W1] -> H (aliases A1), then combine -> zb
    mfma_gemm_kernel<256, 3, 384, 128, false>
        <<<2346, 256, 0, stream>>>(y1, wc2, conv2_b, H, N_NODES, 782);
    combine2_kernel<<<(N_NODES + 3) / 4, 256, 0, stream>>>(ptrb, esort, H, zb);

    // 6) decode
    decode_kernel<<<(N_PAIRS + 3) / 4, 256, 0, stream>>>(zb, dec_index, fc_w, fc_b, out);
}